// Round 1
// baseline (582.019 us; speedup 1.0000x reference)
//
#include <hip/hip_runtime.h>
#include <hip/hip_bf16.h>

#define EMBED 1024
#define NHEADS 16
#define HDIM 64
#define BATCH 4
#define SEQ 2048
#define MROWS (BATCH*SEQ)   // 8192
#define QKVN (3*EMBED)      // 3072
#define KDIM 1024

typedef __bf16 bf16;
typedef __bf16 bf16x4 __attribute__((ext_vector_type(4)));
typedef __bf16 bf16x8 __attribute__((ext_vector_type(8)));
typedef float f32x4 __attribute__((ext_vector_type(4)));

// ---------------- fp32 -> bf16 convert ----------------
__global__ void cvt_bf16(const float* __restrict__ src, bf16* __restrict__ dst, int n4) {
    int i = blockIdx.x * blockDim.x + threadIdx.x;
    if (i < n4) {
        float4 f = ((const float4*)src)[i];
        bf16x4 o;
        o[0] = (bf16)f.x; o[1] = (bf16)f.y; o[2] = (bf16)f.z; o[3] = (bf16)f.w;
        *((bf16x4*)dst + i) = o;
    }
}

// ---------------- 128x128 bf16 GEMM, B^T layout (y = A @ B^T + bias) ----------------
// MODE 0: QKV projection epilogue -> scatter to Q (scaled 1/8), K, V^T (all bf16)
// MODE 1: plain fp32 output + bias
template<int MODE>
__launch_bounds__(256)
__global__ void gemm_bt(const bf16* __restrict__ A, const bf16* __restrict__ B,
                        const float* __restrict__ bias,
                        float* __restrict__ outF,
                        bf16* __restrict__ Qb, bf16* __restrict__ Kb, bf16* __restrict__ Vt)
{
    __shared__ bf16 Alds[128][32];
    __shared__ bf16 Blds[128][32];
    const int tid = threadIdx.x;
    const int l = tid & 63, w = tid >> 6;
    const int wr = w >> 1, wc = w & 1;
    const int tM = blockIdx.y * 128, tN = blockIdx.x * 128;

    f32x4 acc[4][4] = {};
    const bf16* Abase = A + (size_t)tM * KDIM;
    const bf16* Bbase = B + (size_t)tN * KDIM;

    for (int k0 = 0; k0 < KDIM; k0 += 32) {
        #pragma unroll
        for (int t = 0; t < 2; ++t) {
            int idx = t * 256 + tid;
            int row = idx >> 2;
            int kc = (idx & 3) * 8;
            __builtin_amdgcn_global_load_lds(
                (const __attribute__((address_space(1))) void*)(Abase + (size_t)row * KDIM + k0 + kc),
                (__attribute__((address_space(3))) void*)((char*)&Alds[0][0] + idx * 16),
                16, 0, 0);
            __builtin_amdgcn_global_load_lds(
                (const __attribute__((address_space(1))) void*)(Bbase + (size_t)row * KDIM + k0 + kc),
                (__attribute__((address_space(3))) void*)((char*)&Blds[0][0] + idx * 16),
                16, 0, 0);
        }
        __syncthreads();
        bf16x8 a[4], b[4];
        #pragma unroll
        for (int i = 0; i < 4; ++i)
            a[i] = *(const bf16x8*)&Alds[wr * 64 + i * 16 + (l & 15)][(l >> 4) * 8];
        #pragma unroll
        for (int j = 0; j < 4; ++j)
            b[j] = *(const bf16x8*)&Blds[wc * 64 + j * 16 + (l & 15)][(l >> 4) * 8];
        #pragma unroll
        for (int i = 0; i < 4; ++i)
            #pragma unroll
            for (int j = 0; j < 4; ++j)
                acc[i][j] = __builtin_amdgcn_mfma_f32_16x16x32_bf16(a[i], b[j], acc[i][j], 0, 0, 0);
        __syncthreads();
    }

    #pragma unroll
    for (int i = 0; i < 4; ++i) {
        #pragma unroll
        for (int j = 0; j < 4; ++j) {
            int n = tN + wc * 64 + j * 16 + (l & 15);
            float bv = bias[n];
            #pragma unroll
            for (int r = 0; r < 4; ++r) {
                int m = tM + wr * 64 + i * 16 + (l >> 4) * 4 + r;
                float v = acc[i][j][r] + bv;
                if (MODE == 1) {
                    outF[(size_t)m * EMBED + n] = v;
                } else {
                    int which = n >> 10, nn = n & 1023;
                    int hd = nn >> 6, d = nn & 63;
                    int bidx = m >> 11, ns = m & 2047;
                    int bh = bidx * NHEADS + hd;
                    if (which == 0)
                        Qb[((size_t)bh * SEQ + ns) * HDIM + d] = (bf16)(v * 0.125f); // fold 1/sqrt(64)
                    else if (which == 1)
                        Kb[((size_t)bh * SEQ + ns) * HDIM + d] = (bf16)v;
                    else
                        Vt[((size_t)bh * HDIM + d) * SEQ + ns] = (bf16)v;
                }
            }
        }
    }
}

// ---------------- flash attention: 4 independent waves, 16 q-rows each ----------------
__launch_bounds__(256)
__global__ void attn_kernel(const bf16* __restrict__ Qb, const bf16* __restrict__ Kb,
                            const bf16* __restrict__ Vt, bf16* __restrict__ AO)
{
    __shared__ bf16 Plds[4][16][40];   // per-wave P buffer, padded stride 40 elems
    const int tid = threadIdx.x, l = tid & 63, w = tid >> 6;
    const int bh = blockIdx.x >> 5;    // 32 q-tiles of 64 rows per (b,h)
    const int qt = blockIdx.x & 31;
    const int q0 = qt * 64 + w * 16;
    const bf16* Qh = Qb + (size_t)bh * SEQ * HDIM;
    const bf16* Kh = Kb + (size_t)bh * SEQ * HDIM;
    const bf16* Vh = Vt + (size_t)bh * HDIM * SEQ;

    bf16x8 qf[2];
    #pragma unroll
    for (int h = 0; h < 2; ++h)
        qf[h] = *(const bf16x8*)&Qh[(size_t)(q0 + (l & 15)) * HDIM + h * 32 + (l >> 4) * 8];

    f32x4 O[4] = {};
    float mrow[4], lrow[4];
    #pragma unroll
    for (int r = 0; r < 4; ++r) { mrow[r] = -1e30f; lrow[r] = 0.f; }

    for (int kv0 = 0; kv0 < SEQ; kv0 += 32) {
        f32x4 s[2] = {};
        #pragma unroll
        for (int c = 0; c < 2; ++c) {
            #pragma unroll
            for (int h = 0; h < 2; ++h) {
                bf16x8 kf = *(const bf16x8*)&Kh[(size_t)(kv0 + c * 16 + (l & 15)) * HDIM + h * 32 + (l >> 4) * 8];
                s[c] = __builtin_amdgcn_mfma_f32_16x16x32_bf16(qf[h], kf, s[c], 0, 0, 0);
            }
        }
        // online softmax: lane's rows are (l>>4)*4 + r, cols c*16 + (l&15)
        float p0[4], p1[4], corr[4];
        #pragma unroll
        for (int r = 0; r < 4; ++r) {
            float cm = fmaxf(s[0][r], s[1][r]);
            cm = fmaxf(cm, __shfl_xor(cm, 1));
            cm = fmaxf(cm, __shfl_xor(cm, 2));
            cm = fmaxf(cm, __shfl_xor(cm, 4));
            cm = fmaxf(cm, __shfl_xor(cm, 8));
            float mn = fmaxf(mrow[r], cm);
            corr[r] = __expf(mrow[r] - mn);
            mrow[r] = mn;
            p0[r] = __expf(s[0][r] - mn);
            p1[r] = __expf(s[1][r] - mn);
            float rs = p0[r] + p1[r];
            rs += __shfl_xor(rs, 1);
            rs += __shfl_xor(rs, 2);
            rs += __shfl_xor(rs, 4);
            rs += __shfl_xor(rs, 8);
            lrow[r] = lrow[r] * corr[r] + rs;
        }
        #pragma unroll
        for (int dt = 0; dt < 4; ++dt)
            #pragma unroll
            for (int r = 0; r < 4; ++r)
                O[dt][r] *= corr[r];
        // P -> LDS (C-layout) then read back as A-fragment
        #pragma unroll
        for (int r = 0; r < 4; ++r) {
            int row = (l >> 4) * 4 + r;
            Plds[w][row][l & 15] = (bf16)p0[r];
            Plds[w][row][16 + (l & 15)] = (bf16)p1[r];
        }
        asm volatile("s_waitcnt lgkmcnt(0)" ::: "memory");
        bf16x8 pa = *(const bf16x8*)&Plds[w][l & 15][(l >> 4) * 8];
        #pragma unroll
        for (int dt = 0; dt < 4; ++dt) {
            bf16x8 vf = *(const bf16x8*)&Vh[(size_t)(dt * 16 + (l & 15)) * SEQ + kv0 + (l >> 4) * 8];
            O[dt] = __builtin_amdgcn_mfma_f32_16x16x32_bf16(pa, vf, O[dt], 0, 0, 0);
        }
    }
    // normalize + write attn output as [B*N][E] bf16, e = h*64 + d
    const int b = bh >> 4, hd = bh & 15;
    #pragma unroll
    for (int dt = 0; dt < 4; ++dt) {
        #pragma unroll
        for (int r = 0; r < 4; ++r) {
            int m = b * SEQ + q0 + (l >> 4) * 4 + r;
            int e = hd * HDIM + dt * 16 + (l & 15);
            AO[(size_t)m * EMBED + e] = (bf16)(O[dt][r] / lrow[r]);
        }
    }
}

extern "C" void kernel_launch(void* const* d_in, const int* in_sizes, int n_in,
                              void* d_out, int out_size, void* d_ws, size_t ws_size,
                              hipStream_t stream) {
    const float* x     = (const float*)d_in[0];
    const float* qkv_w = (const float*)d_in[1];
    const float* qkv_b = (const float*)d_in[2];
    const float* out_w = (const float*)d_in[3];
    const float* out_b = (const float*)d_in[4];
    float* out = (float*)d_out;

    char* ws = (char*)d_ws;
    bf16* xb  = (bf16*)(ws);                         // 8192*1024
    bf16* qwb = (bf16*)(ws + 16777216);              // 3072*1024
    bf16* owb = (bf16*)(ws + 23068672);              // 1024*1024
    bf16* Qb  = (bf16*)(ws + 25165824);              // 64*2048*64
    bf16* Kb  = (bf16*)(ws + 41943040);              // 64*2048*64
    bf16* Vt  = (bf16*)(ws + 58720256);              // 64*64*2048
    bf16* AO  = (bf16*)(ws + 75497472);              // 8192*1024  (end 92274688)

    // converts
    cvt_bf16<<<(MROWS * EMBED / 4 + 255) / 256, 256, 0, stream>>>(x, xb, MROWS * EMBED / 4);
    cvt_bf16<<<(QKVN * KDIM / 4 + 255) / 256, 256, 0, stream>>>(qkv_w, qwb, QKVN * KDIM / 4);
    cvt_bf16<<<(EMBED * KDIM / 4 + 255) / 256, 256, 0, stream>>>(out_w, owb, EMBED * KDIM / 4);

    // QKV projection + scatter
    gemm_bt<0><<<dim3(QKVN / 128, MROWS / 128), 256, 0, stream>>>(
        xb, qwb, qkv_b, nullptr, Qb, Kb, Vt);

    // attention
    attn_kernel<<<BATCH * NHEADS * (SEQ / 64), 256, 0, stream>>>(Qb, Kb, Vt, AO);

    // output projection
    gemm_bt<1><<<dim3(EMBED / 128, MROWS / 128), 256, 0, stream>>>(
        AO, owb, out_b, out, nullptr, nullptr, nullptr);
}

// Round 3
// 468.784 us; speedup vs baseline: 1.2416x; 1.2416x over previous
//
#include <hip/hip_runtime.h>
#include <hip/hip_bf16.h>

#define EMBED 1024
#define NHEADS 16
#define HDIM 64
#define BATCH 4
#define SEQ 2048
#define MROWS (BATCH*SEQ)   // 8192
#define QKVN (3*EMBED)      // 3072
#define KDIM 1024

typedef __bf16 bf16;
typedef __bf16 bf16x4 __attribute__((ext_vector_type(4)));
typedef __bf16 bf16x8 __attribute__((ext_vector_type(8)));
typedef float f32x4 __attribute__((ext_vector_type(4)));
typedef float f32x16 __attribute__((ext_vector_type(16)));

// scale = 1/sqrt(64) * log2(e), folded into Q so softmax uses raw v_exp_f32 (2^x)
#define QSCALE 0.18033688011112042f

// ---------------- fp32 -> bf16 convert ----------------
__global__ void cvt_bf16(const float* __restrict__ src, bf16* __restrict__ dst, int n4) {
    int i = blockIdx.x * blockDim.x + threadIdx.x;
    if (i < n4) {
        float4 f = ((const float4*)src)[i];
        bf16x4 o;
        o[0] = (bf16)f.x; o[1] = (bf16)f.y; o[2] = (bf16)f.z; o[3] = (bf16)f.w;
        *((bf16x4*)dst + i) = o;
    }
}

// ---------------- 128x128 bf16 GEMM, B^T layout (y = A @ B^T + bias) ----------------
template<int MODE>
__launch_bounds__(256)
__global__ void gemm_bt(const bf16* __restrict__ A, const bf16* __restrict__ B,
                        const float* __restrict__ bias,
                        float* __restrict__ outF,
                        bf16* __restrict__ Qb, bf16* __restrict__ Kb, bf16* __restrict__ Vt)
{
    __shared__ bf16 Alds[128][32];
    __shared__ bf16 Blds[128][32];
    const int tid = threadIdx.x;
    const int l = tid & 63, w = tid >> 6;
    const int wr = w >> 1, wc = w & 1;
    const int tM = blockIdx.y * 128, tN = blockIdx.x * 128;

    f32x4 acc[4][4] = {};
    const bf16* Abase = A + (size_t)tM * KDIM;
    const bf16* Bbase = B + (size_t)tN * KDIM;

    for (int k0 = 0; k0 < KDIM; k0 += 32) {
        #pragma unroll
        for (int t = 0; t < 2; ++t) {
            int idx = t * 256 + tid;
            int row = idx >> 2;
            int kc = (idx & 3) * 8;
            __builtin_amdgcn_global_load_lds(
                (const __attribute__((address_space(1))) void*)(Abase + (size_t)row * KDIM + k0 + kc),
                (__attribute__((address_space(3))) void*)((char*)&Alds[0][0] + idx * 16),
                16, 0, 0);
            __builtin_amdgcn_global_load_lds(
                (const __attribute__((address_space(1))) void*)(Bbase + (size_t)row * KDIM + k0 + kc),
                (__attribute__((address_space(3))) void*)((char*)&Blds[0][0] + idx * 16),
                16, 0, 0);
        }
        __syncthreads();
        bf16x8 a[4], b[4];
        #pragma unroll
        for (int i = 0; i < 4; ++i)
            a[i] = *(const bf16x8*)&Alds[wr * 64 + i * 16 + (l & 15)][(l >> 4) * 8];
        #pragma unroll
        for (int j = 0; j < 4; ++j)
            b[j] = *(const bf16x8*)&Blds[wc * 64 + j * 16 + (l & 15)][(l >> 4) * 8];
        #pragma unroll
        for (int i = 0; i < 4; ++i)
            #pragma unroll
            for (int j = 0; j < 4; ++j)
                acc[i][j] = __builtin_amdgcn_mfma_f32_16x16x32_bf16(a[i], b[j], acc[i][j], 0, 0, 0);
        __syncthreads();
    }

    #pragma unroll
    for (int i = 0; i < 4; ++i) {
        #pragma unroll
        for (int j = 0; j < 4; ++j) {
            int n = tN + wc * 64 + j * 16 + (l & 15);
            float bv = bias[n];
            #pragma unroll
            for (int r = 0; r < 4; ++r) {
                int m = tM + wr * 64 + i * 16 + (l >> 4) * 4 + r;
                float v = acc[i][j][r] + bv;
                if (MODE == 1) {
                    outF[(size_t)m * EMBED + n] = v;
                } else {
                    int which = n >> 10, nn = n & 1023;
                    int hd = nn >> 6, d = nn & 63;
                    int bidx = m >> 11, ns = m & 2047;
                    int bh = bidx * NHEADS + hd;
                    if (which == 0)
                        Qb[((size_t)bh * SEQ + ns) * HDIM + d] = (bf16)(v * QSCALE);
                    else if (which == 1)
                        Kb[((size_t)bh * SEQ + ns) * HDIM + d] = (bf16)v;
                    else
                        Vt[((size_t)bh * HDIM + d) * SEQ + ns] = (bf16)v;
                }
            }
        }
    }
}

// ---------------- flash attention: 4 warps/block, 32 q-rows per warp ----------------
// Swapped QK^T: S^T[kpos][q] = mfma32x32x16(A=K, B=Q); q = lane&31 for both S and O^T.
// PV: O^T[d][q] = mfma(A=V^T, B=P^T), with V loaded in tau-permuted k-order
// (tau(hi,j) = 4*hi + (j&3) + 8*(j>>2)) matching P's natural C-layout, so the
// P fragment is each lane's own 16 values cast to bf16 -- no cross-lane exchange.
__launch_bounds__(256)
__global__ void attn_kernel(const bf16* __restrict__ Qb, const bf16* __restrict__ Kb,
                            const bf16* __restrict__ Vt, bf16* __restrict__ AO)
{
    const int tid = threadIdx.x, l = tid & 63, w = tid >> 6;
    const int lo5 = l & 31, hi = l >> 5;
    // XCD-aware bijective swizzle: 1024 blocks, 8 XCDs
    int bid = blockIdx.x;
    int swz = (bid & 7) * 128 + (bid >> 3);
    const int bh = swz >> 4;
    const int qt = swz & 15;
    const int q0 = qt * 128 + w * 32;

    const bf16* Qh = Qb + (size_t)bh * SEQ * HDIM;
    const bf16* Kh = Kb + (size_t)bh * SEQ * HDIM;
    const bf16* Vh = Vt + (size_t)bh * HDIM * SEQ;

    // Q fragments (B operand): col = q = lo5, k-slice kk*16 + hi*8 + j
    bf16x8 qf[4];
    #pragma unroll
    for (int kk = 0; kk < 4; ++kk)
        qf[kk] = *(const bf16x8*)&Qh[(size_t)(q0 + lo5) * HDIM + kk * 16 + hi * 8];

    f32x16 O0 = {}, O1 = {};
    float m = -1e30f, lsum = 0.f;

    union B8 { bf16x4 h[2]; bf16x8 v; };

    for (int kv0 = 0; kv0 < SEQ; kv0 += 32) {
        // K frags (A operand): row = kpos = lo5, k-slice kk*16 + hi*8 + j
        const bf16* Krow = &Kh[(size_t)(kv0 + lo5) * HDIM + hi * 8];
        bf16x8 kf0 = *(const bf16x8*)(Krow);
        bf16x8 kf1 = *(const bf16x8*)(Krow + 16);
        bf16x8 kf2 = *(const bf16x8*)(Krow + 32);
        bf16x8 kf3 = *(const bf16x8*)(Krow + 48);

        // V frags (A operand), tau-permuted: element j holds
        // V^T[d][kv0 + c*16 + 4*hi + (j&3) + 8*(j>>2)]
        const bf16* Vrow0 = &Vh[(size_t)lo5 * SEQ + kv0 + 4 * hi];
        const bf16* Vrow1 = Vrow0 + (size_t)32 * SEQ;
        B8 vf00, vf01, vf10, vf11;
        vf00.h[0] = *(const bf16x4*)(Vrow0);
        vf00.h[1] = *(const bf16x4*)(Vrow0 + 8);
        vf01.h[0] = *(const bf16x4*)(Vrow0 + 16);
        vf01.h[1] = *(const bf16x4*)(Vrow0 + 24);
        vf10.h[0] = *(const bf16x4*)(Vrow1);
        vf10.h[1] = *(const bf16x4*)(Vrow1 + 8);
        vf11.h[0] = *(const bf16x4*)(Vrow1 + 16);
        vf11.h[1] = *(const bf16x4*)(Vrow1 + 24);

        // S^T[kpos][q]: kpos = (r&3)+8*(r>>2)+4*hi, q = lo5
        f32x16 S = {};
        S = __builtin_amdgcn_mfma_f32_32x32x16_bf16(kf0, qf[0], S, 0, 0, 0);
        S = __builtin_amdgcn_mfma_f32_32x32x16_bf16(kf1, qf[1], S, 0, 0, 0);
        S = __builtin_amdgcn_mfma_f32_32x32x16_bf16(kf2, qf[2], S, 0, 0, 0);
        S = __builtin_amdgcn_mfma_f32_32x32x16_bf16(kf3, qf[3], S, 0, 0, 0);

        // row max over the 32 kpos this q-column sees
        float x0 = fmaxf(S[0], S[1]),  x1 = fmaxf(S[2], S[3]);
        float x2 = fmaxf(S[4], S[5]),  x3 = fmaxf(S[6], S[7]);
        float x4 = fmaxf(S[8], S[9]),  x5 = fmaxf(S[10], S[11]);
        float x6 = fmaxf(S[12], S[13]), x7 = fmaxf(S[14], S[15]);
        x0 = fmaxf(x0, x1); x2 = fmaxf(x2, x3); x4 = fmaxf(x4, x5); x6 = fmaxf(x6, x7);
        x0 = fmaxf(x0, x2); x4 = fmaxf(x4, x6);
        float cm = fmaxf(x0, x4);
        cm = fmaxf(cm, __shfl_xor(cm, 32));

        // exact online softmax (rescale every tile)
        float mn = fmaxf(m, cm);
        float corr = __builtin_amdgcn_exp2f(m - mn);
        O0 *= corr; O1 *= corr; lsum *= corr;
        m = mn;

        float p[16];
        #pragma unroll
        for (int r = 0; r < 16; ++r)
            p[r] = __builtin_amdgcn_exp2f(S[r] - m);

        float s0 = (p[0] + p[1]) + (p[2] + p[3]);
        float s1 = (p[4] + p[5]) + (p[6] + p[7]);
        float s2 = (p[8] + p[9]) + (p[10] + p[11]);
        float s3 = (p[12] + p[13]) + (p[14] + p[15]);
        float tot = (s0 + s1) + (s2 + s3);
        tot += __shfl_xor(tot, 32);
        lsum += tot;

        // P fragment = own values, cast to bf16 (pairs with tau-permuted V)
        bf16x8 pa0, pa1;
        #pragma unroll
        for (int r = 0; r < 8; ++r) { pa0[r] = (bf16)p[r]; pa1[r] = (bf16)p[r + 8]; }

        // O^T[d][q] += V^T * P^T
        O0 = __builtin_amdgcn_mfma_f32_32x32x16_bf16(vf00.v, pa0, O0, 0, 0, 0);
        O0 = __builtin_amdgcn_mfma_f32_32x32x16_bf16(vf01.v, pa1, O0, 0, 0, 0);
        O1 = __builtin_amdgcn_mfma_f32_32x32x16_bf16(vf10.v, pa0, O1, 0, 0, 0);
        O1 = __builtin_amdgcn_mfma_f32_32x32x16_bf16(vf11.v, pa1, O1, 0, 0, 0);
    }

    float linv = 1.0f / lsum;
    const int b = bh >> 4, hd = bh & 15;
    bf16* outp = &AO[(size_t)(b * SEQ + q0 + lo5) * EMBED + hd * HDIM];
    #pragma unroll
    for (int g = 0; g < 4; ++g) {
        bf16x4 o0, o1;
        #pragma unroll
        for (int r4 = 0; r4 < 4; ++r4) {
            o0[r4] = (bf16)(O0[g * 4 + r4] * linv);
            o1[r4] = (bf16)(O1[g * 4 + r4] * linv);
        }
        *(bf16x4*)&outp[g * 8 + hi * 4] = o0;
        *(bf16x4*)&outp[32 + g * 8 + hi * 4] = o1;
    }
}

extern "C" void kernel_launch(void* const* d_in, const int* in_sizes, int n_in,
                              void* d_out, int out_size, void* d_ws, size_t ws_size,
                              hipStream_t stream) {
    const float* x     = (const float*)d_in[0];
    const float* qkv_w = (const float*)d_in[1];
    const float* qkv_b = (const float*)d_in[2];
    const float* out_w = (const float*)d_in[3];
    const float* out_b = (const float*)d_in[4];
    float* out = (float*)d_out;

    char* ws = (char*)d_ws;
    bf16* xb  = (bf16*)(ws);                         // 8192*1024
    bf16* qwb = (bf16*)(ws + 16777216);              // 3072*1024
    bf16* owb = (bf16*)(ws + 23068672);              // 1024*1024
    bf16* Qb  = (bf16*)(ws + 25165824);              // 64*2048*64
    bf16* Kb  = (bf16*)(ws + 41943040);              // 64*2048*64
    bf16* Vt  = (bf16*)(ws + 58720256);              // 64*64*2048
    bf16* AO  = (bf16*)(ws + 75497472);              // 8192*1024  (end 92274688)

    cvt_bf16<<<(MROWS * EMBED / 4 + 255) / 256, 256, 0, stream>>>(x, xb, MROWS * EMBED / 4);
    cvt_bf16<<<(QKVN * KDIM / 4 + 255) / 256, 256, 0, stream>>>(qkv_w, qwb, QKVN * KDIM / 4);
    cvt_bf16<<<(EMBED * KDIM / 4 + 255) / 256, 256, 0, stream>>>(out_w, owb, EMBED * KDIM / 4);

    gemm_bt<0><<<dim3(QKVN / 128, MROWS / 128), 256, 0, stream>>>(
        xb, qwb, qkv_b, nullptr, Qb, Kb, Vt);

    attn_kernel<<<BATCH * NHEADS * (SEQ / 128), 256, 0, stream>>>(Qb, Kb, Vt, AO);

    gemm_bt<1><<<dim3(EMBED / 128, MROWS / 128), 256, 0, stream>>>(
        AO, owb, out_b, out, nullptr, nullptr, nullptr);
}